// Round 11
// baseline (74.405 us; speedup 1.0000x reference)
//
#include <hip/hip_runtime.h>
#include <math.h>

#define SEQ   4096
#define HD    64
#define NH    16
#define WHALF 256
#define QB    128    // queries per block = 8 waves x 16
#define KT    128    // keys staged per barrier
#define KSTR  72     // K plane d-stride (shorts): 144B rows -> b128 R/W at 8-phase bank floor
#define VSTR  136    // V plane key-stride (shorts): 272B rows -> b128 R/W at 8-phase bank floor
#define KPLANE (KT * KSTR)   // 9216 shorts
#define VPLANE (HD * VSTR)   // 8704 shorts
#define BUFSZ  (KPLANE + VPLANE)

typedef __attribute__((ext_vector_type(8))) __bf16 bf16x8;
typedef __attribute__((ext_vector_type(8))) short short8v;
typedef __attribute__((ext_vector_type(4))) float f32x4;

__device__ __forceinline__ short bf16bits(float x) {
    __bf16 b = (__bf16)x;            // RTN
    return __builtin_bit_cast(short, b);
}

#define MFMA32(A, B, C) __builtin_amdgcn_mfma_f32_16x16x32_bf16((A), (B), (C), 0, 0, 0)

#if __has_builtin(__builtin_amdgcn_exp2f)
#define EXP2F(x) __builtin_amdgcn_exp2f(x)
#else
#define EXP2F(x) __exp2f(x)
#endif

// LDS-ordering barrier that does NOT drain vmcnt: global prefetch loads
// (register-destined, same-wave-consumed) ride through. T3/T4 pattern.
#define TILE_BARRIER() asm volatile("s_waitcnt lgkmcnt(0)\n\ts_barrier" ::: "memory")

__global__ __launch_bounds__(512, 4)
void swa_mfma11_kernel(const float* __restrict__ q,
                       const float* __restrict__ k,
                       const float* __restrict__ v,
                       float* __restrict__ out) {
    // double-buffered: [buf][K plane | V plane] ; 71680 B total -> 2 blocks/CU
    __shared__ short smem[2 * BUFSZ];

    // ---- XCD-aware bijective swizzle: 512 blocks = 8 XCDs x 64; head-major chunks ----
    const int orig = blockIdx.x;
    const int work = ((orig & 7) << 6) + (orig >> 3);
    const int h    = work >> 5;
    const int q0   = (work & 31) * QB;

    const int t    = threadIdx.x;
    const int lane = t & 63;
    const int w    = t >> 6;             // wave 0..7
    const int n15  = lane & 15;
    const int g    = lane >> 4;          // 0..3
    const int qrow = q0 + w * 16 + n15;  // this lane's query

    // scores in log2 domain (fold 1/sqrt(64)*log2(e) into Q); NO max-shift:
    // softmax is shift-invariant and scores are O(10) in the log2 domain.
    const float SCALE = 0.125f * 1.44269504088896340736f;

    // ---- Q fragments (B-operand of S^T = K·Q^T), pre-scaled, plain bf16 ----
    bf16x8 qf[2];
    {
        const float* qp = q + ((size_t)h * SEQ + qrow) * HD;
        #pragma unroll
        for (int c = 0; c < 2; ++c) {
            const float4* p4 = reinterpret_cast<const float4*>(qp + 32 * c + 8 * g);
            float4 a = p4[0], b = p4[1];
            float xs[8] = {a.x, a.y, a.z, a.w, b.x, b.y, b.z, b.w};
            short8v q8;
            #pragma unroll
            for (int j = 0; j < 8; ++j) q8[j] = bf16bits(xs[j] * SCALE);
            qf[c] = __builtin_bit_cast(bf16x8, q8);
        }
    }

    // ones A-fragment for the lsum MFMA (row 0 of A = ones): register constant
    bf16x8 ones8;
    {
        short8v o8;
        const short ov = (n15 == 0) ? (short)0x3F80 : (short)0;
        #pragma unroll
        for (int j = 0; j < 8; ++j) o8[j] = ov;
        ones8 = __builtin_bit_cast(bf16x8, o8);
    }

    f32x4 accO[4];
    #pragma unroll
    for (int dt = 0; dt < 4; ++dt) accO[dt] = (f32x4){0.f, 0.f, 0.f, 0.f};
    f32x4 accL = (f32x4){0.f, 0.f, 0.f, 0.f};   // lsum lands in reg 0 of g=0 lanes

    int k0 = q0 - WHALF;           if (k0 < 0) k0 = 0;
    int k1 = q0 + QB - 1 + WHALF;  if (k1 > SEQ - 1) k1 = SEQ - 1;
    const int nt = (k1 + 1 - k0) >> 7;   // always 5 for this problem shape

    const int wqmin = q0 + w * 16;
    const int wqmax = wqmin + 15;
    const int wlo   = wqmin - WHALF;   // wave union window
    const int whi   = wqmax + WHALF;

    const float4* kb4 = reinterpret_cast<const float4*>(k + ((size_t)h * SEQ) * HD);
    const float*  vp  = v + ((size_t)h * SEQ) * HD;

    // ---- dual prefetch register sets (2 tiles in flight, counted vmcnt) ----
    float4 kregA[4], kregB[4];
    float  vregA[16], vregB[16];

    auto LOADT = [&](float4 (&kr)[4], float (&vr)[16], int kt_) {
        #pragma unroll
        for (int i2 = 0; i2 < 4; ++i2)
            kr[i2] = kb4[(size_t)kt_ * 16 + t * 4 + i2];
        #pragma unroll
        for (int j = 0; j < 16; ++j)
            vr[j] = vp[(size_t)(kt_ + 16 * w + j) * HD + lane];
    };

    // ---- stage regs -> buffer b.  K rows PERMUTED (within each 32-key chunk)
    // so the QK D-fragment hands each lane keys 8g..8g+7 (K=32 PV B-order):
    // physical key p: R = (p & 96) | perm5(p & 31), perm5 validated in R7.
    auto STAGE = [&](int b, const float4 (&kr)[4], const float (&vr)[16]) {
        short* Kb = smem + b * BUFSZ;
        short* Vb = Kb + KPLANE;

        const int p  = t >> 2;           // physical key row (0..127); 4 threads/row
        const int q5 = p & 31;
        const int R  = (p & 96) + (((q5 >> 2) & 1) << 4) + ((q5 >> 3) << 2) + (q5 & 3);

        const float* kf = reinterpret_cast<const float*>(&kr[0]);
        short8v k8a, k8b;
        #pragma unroll
        for (int j = 0; j < 8; ++j) {
            k8a[j] = bf16bits(kf[j]);
            k8b[j] = bf16bits(kf[8 + j]);
        }
        *reinterpret_cast<short8v*>(&Kb[R * KSTR + (t & 3) * 16])     = k8a;
        *reinterpret_cast<short8v*>(&Kb[R * KSTR + (t & 3) * 16 + 8]) = k8b;

        short8v v8a, v8b;
        #pragma unroll
        for (int j = 0; j < 8; ++j) {
            v8a[j] = bf16bits(vr[j]);
            v8b[j] = bf16bits(vr[8 + j]);
        }
        *reinterpret_cast<short8v*>(&Vb[lane * VSTR + 16 * w])     = v8a;  // [d=lane][key 16w..]
        *reinterpret_cast<short8v*>(&Vb[lane * VSTR + 16 * w + 8]) = v8b;
    };

    LOADT(kregA, vregA, k0);
    STAGE(0, kregA, vregA);              // consumes set A
    if (nt > 1) LOADT(kregB, vregB, k0 + KT);
    TILE_BARRIER();

    for (int i = 0; i < nt; ++i) {
        const int kt  = k0 + i * KT;
        const int cur = i & 1;

        if (i + 1 < nt) {
            // prefetch tile i+2 into the set STAGE(i) consumed last iter;
            // then stage tile i+1 from the other set (compiler emits a
            // COUNTED vmcnt that skips the 20 just-issued loads).
            const int ktn = k0 + ((i + 2 < nt) ? (i + 2) : (nt - 1)) * KT;
            if (cur) { LOADT(kregB, vregB, ktn); STAGE(cur ^ 1, kregA, vregA); }
            else     { LOADT(kregA, vregA, ktn); STAGE(cur ^ 1, kregB, vregB); }
        }

        const short* Kb = smem + cur * BUFSZ;
        const short* Vb = Kb + KPLANE;

        #pragma unroll
        for (int kc = 0; kc < 4; ++kc) {
            const int cb = kt + kc * 32;
            if (cb > whi || cb + 31 < wlo) continue;   // wave-uniform chunk skip

            // ---- S^T = K·Q^T (two chained 16x16x32 per 16-key half) ----
            f32x4 S[2];
            __builtin_amdgcn_s_setprio(1);
            #pragma unroll
            for (int s = 0; s < 2; ++s) {
                const int krow = (kc * 32 + s * 16 + n15) * KSTR + 8 * g;
                bf16x8 k0f = __builtin_bit_cast(bf16x8, *reinterpret_cast<const short8v*>(&Kb[krow]));
                bf16x8 k1f = __builtin_bit_cast(bf16x8, *reinterpret_cast<const short8v*>(&Kb[krow + 32]));
                f32x4 a = (f32x4){0.f, 0.f, 0.f, 0.f};
                a = MFMA32(k0f, qf[0], a);
                a = MFMA32(k1f, qf[1], a);
                S[s] = a;
            }
            __builtin_amdgcn_s_setprio(0);

            // lane's 8 scores are keys cb+8g .. cb+8g+7:  sc[j] = S[j>>2][j&3]
            // P = exp2(sc) directly (no shift); masked -> exp2(-1e30) == 0
            short8v p8s;
            const bool interior = (cb >= wqmax - WHALF) && (cb + 31 <= wqmin + WHALF);
            if (interior) {
                #pragma unroll
                for (int j = 0; j < 8; ++j)
                    p8s[j] = bf16bits(EXP2F(S[j >> 2][j & 3]));
            } else {
                const int kbase = cb + 8 * g;
                #pragma unroll
                for (int j = 0; j < 8; ++j) {
                    int key = kbase + j;
                    bool valid = (key >= qrow - WHALF) && (key <= qrow + WHALF);
                    p8s[j] = bf16bits(EXP2F(valid ? S[j >> 2][j & 3] : -1e30f));
                }
            }
            bf16x8 p8 = __builtin_bit_cast(bf16x8, p8s);

            // ---- PV: O^T += V^T · P^T via 16x16x32, + register-ones lsum MFMA ----
            __builtin_amdgcn_s_setprio(1);
            #pragma unroll
            for (int dt = 0; dt < 4; ++dt) {
                const int vrow = (dt * 16 + n15) * VSTR + kc * 32 + 8 * g;
                bf16x8 vf = __builtin_bit_cast(bf16x8, *reinterpret_cast<const short8v*>(&Vb[vrow]));
                accO[dt] = MFMA32(vf, p8, accO[dt]);
            }
            accL = MFMA32(ones8, p8, accL);   // row 0 = sum_k p[k] for query n15
            __builtin_amdgcn_s_setprio(0);
        }

        if (i + 1 < nt) TILE_BARRIER();    // lgkm-only: prefetch rides through
    }

    // ---- epilogue: lsum sits in accL[0] of the g=0 lane for each query ----
    const float lsum = __shfl(accL[0], n15);   // broadcast from lane id n15 (g=0 block)
    const float inv  = 1.0f / lsum;
    float* op = out + ((size_t)h * SEQ + qrow) * HD;
    #pragma unroll
    for (int dt = 0; dt < 4; ++dt) {
        *reinterpret_cast<f32x4*>(op + dt * 16 + 4 * g) = accO[dt] * inv;
    }
}

extern "C" void kernel_launch(void* const* d_in, const int* in_sizes, int n_in,
                              void* d_out, int out_size, void* d_ws, size_t ws_size,
                              hipStream_t stream) {
    const float* q = (const float*)d_in[0];
    const float* k = (const float*)d_in[1];
    const float* v = (const float*)d_in[2];
    float* out = (float*)d_out;

    dim3 grid(NH * (SEQ / QB));   // 512 blocks (1D for swizzle)
    dim3 block(512);              // 8 waves
    hipLaunchKernelGGL(swa_mfma11_kernel, grid, block, 0, stream, q, k, v, out);
}

// Round 12
// 30.071 us; speedup vs baseline: 2.4743x; 2.4743x over previous
//
#include <hip/hip_runtime.h>
#include <math.h>

#define SEQ   4096
#define HD    64
#define NH    16
#define WHALF 256
#define QB    64     // queries per block = 4 waves x 16
#define KT    64     // keys staged per barrier
#define KSTR  72     // K plane d-stride (shorts): 144B rows -> b128 R/W at 8-phase bank floor
#define VSTR  72     // V plane key-stride (shorts): 144B rows
#define KPLANE (KT * KSTR)   // 4608 shorts
#define VPLANE (HD * VSTR)   // 4608 shorts
#define BUFSZ  (KPLANE + VPLANE)

typedef __attribute__((ext_vector_type(8))) __bf16 bf16x8;
typedef __attribute__((ext_vector_type(8))) short short8v;
typedef __attribute__((ext_vector_type(4))) float f32x4;

__device__ __forceinline__ short bf16bits(float x) {
    __bf16 b = (__bf16)x;            // RTN
    return __builtin_bit_cast(short, b);
}

#define MFMA32(A, B, C) __builtin_amdgcn_mfma_f32_16x16x32_bf16((A), (B), (C), 0, 0, 0)

#if __has_builtin(__builtin_amdgcn_exp2f)
#define EXP2F(x) __builtin_amdgcn_exp2f(x)
#else
#define EXP2F(x) __exp2f(x)
#endif

__global__ __launch_bounds__(256, 4)
void swa_mfma12_kernel(const float* __restrict__ q,
                       const float* __restrict__ k,
                       const float* __restrict__ v,
                       float* __restrict__ out) {
    // double-buffered: [buf][K plane | V plane] ; 36864 B -> 4 blocks/CU
    __shared__ short smem[2 * BUFSZ];

    // ---- XCD-aware bijective swizzle: 1024 blocks = 8 XCDs x 128; head-major ----
    const int orig = blockIdx.x;
    const int work = ((orig & 7) << 7) + (orig >> 3);
    const int h    = work >> 6;          // 64 q-tiles per head -> 2 heads per XCD chunk
    const int q0   = (work & 63) * QB;

    const int t    = threadIdx.x;        // 0..255
    const int lane = t & 63;
    const int w    = t >> 6;             // wave 0..3
    const int n15  = lane & 15;
    const int g    = lane >> 4;          // 0..3
    const int qrow = q0 + w * 16 + n15;  // this lane's query

    // scores in log2 domain (fold 1/sqrt(64)*log2(e) into Q); NO max-shift:
    // softmax is shift-invariant and scores are O(10) in the log2 domain.
    const float SCALE = 0.125f * 1.44269504088896340736f;

    // ---- Q fragments (B-operand of S^T = K·Q^T), pre-scaled, plain bf16 ----
    bf16x8 qf[2];
    {
        const float* qp = q + ((size_t)h * SEQ + qrow) * HD;
        #pragma unroll
        for (int c = 0; c < 2; ++c) {
            const float4* p4 = reinterpret_cast<const float4*>(qp + 32 * c + 8 * g);
            float4 a = p4[0], b = p4[1];
            float xs[8] = {a.x, a.y, a.z, a.w, b.x, b.y, b.z, b.w};
            short8v q8;
            #pragma unroll
            for (int j = 0; j < 8; ++j) q8[j] = bf16bits(xs[j] * SCALE);
            qf[c] = __builtin_bit_cast(bf16x8, q8);
        }
    }

    // ones A-fragment for the lsum MFMA (row 0 of A = ones): register constant
    bf16x8 ones8;
    {
        short8v o8;
        const short ov = (n15 == 0) ? (short)0x3F80 : (short)0;
        #pragma unroll
        for (int j = 0; j < 8; ++j) o8[j] = ov;
        ones8 = __builtin_bit_cast(bf16x8, o8);
    }

    f32x4 accO[4];
    #pragma unroll
    for (int dt = 0; dt < 4; ++dt) accO[dt] = (f32x4){0.f, 0.f, 0.f, 0.f};
    f32x4 accL = (f32x4){0.f, 0.f, 0.f, 0.f};   // lsum lands in reg 0 of g=0 lanes

    int k0 = q0 - WHALF;           if (k0 < 0) k0 = 0;
    int k1 = q0 + QB - 1 + WHALF;  if (k1 > SEQ - 1) k1 = SEQ - 1;
    const int nt = (k1 + 1 - k0) >> 6;   // whole 64-key tiles (5..9)

    const int wqmin = q0 + w * 16;
    const int wqmax = wqmin + 15;
    const int wlo   = wqmin - WHALF;   // wave union window
    const int whi   = wqmax + WHALF;

    const float4* kb4 = reinterpret_cast<const float4*>(k + ((size_t)h * SEQ) * HD);
    const float*  vp  = v + ((size_t)h * SEQ) * HD;

    // ---- single-set 2-tile-deep register prefetch (R10-proven codegen form) ----
    float4 kreg[4];
    float  vreg[16];

    #define LOADT(KTV)                                                        \
        {                                                                     \
            const int kt_ = (KTV);                                            \
            _Pragma("unroll")                                                 \
            for (int i2 = 0; i2 < 4; ++i2)                                    \
                kreg[i2] = kb4[(size_t)kt_ * 16 + t * 4 + i2];                \
            _Pragma("unroll")                                                 \
            for (int j = 0; j < 16; ++j)                                      \
                vreg[j] = vp[(size_t)(kt_ + 16 * w + j) * HD + lane];         \
        }

    // ---- stage regs -> buffer b.  K rows PERMUTED (within each 32-key chunk)
    // so the QK D-fragment hands each lane keys 8g..8g+7 (K=32 PV B-order):
    // physical key p: R = (p & 32) | perm5(p & 31), perm5 validated since R7.
    auto STAGE = [&](int b) {
        short* Kb = smem + b * BUFSZ;
        short* Vb = Kb + KPLANE;

        const int p  = t >> 2;           // physical key row (0..63); 4 threads/row
        const int q5 = p & 31;
        const int R  = (p & 32) + (((q5 >> 2) & 1) << 4) + ((q5 >> 3) << 2) + (q5 & 3);

        const float* kf = reinterpret_cast<const float*>(&kreg[0]);
        short8v k8a, k8b;
        #pragma unroll
        for (int j = 0; j < 8; ++j) {
            k8a[j] = bf16bits(kf[j]);
            k8b[j] = bf16bits(kf[8 + j]);
        }
        *reinterpret_cast<short8v*>(&Kb[R * KSTR + (t & 3) * 16])     = k8a;
        *reinterpret_cast<short8v*>(&Kb[R * KSTR + (t & 3) * 16 + 8]) = k8b;

        short8v v8a, v8b;
        #pragma unroll
        for (int j = 0; j < 8; ++j) {
            v8a[j] = bf16bits(vreg[j]);
            v8b[j] = bf16bits(vreg[8 + j]);
        }
        *reinterpret_cast<short8v*>(&Vb[lane * VSTR + 16 * w])     = v8a;  // [d=lane][key 16w..]
        *reinterpret_cast<short8v*>(&Vb[lane * VSTR + 16 * w + 8]) = v8b;
    };

    LOADT(k0);
    STAGE(0);
    if (nt > 1) LOADT(k0 + KT);
    __syncthreads();

    for (int i = 0; i < nt; ++i) {
        const int kt  = k0 + i * KT;
        const int cur = i & 1;

        if (i + 1 < nt) {
            STAGE(cur ^ 1);
            if (i + 2 < nt) LOADT(k0 + (i + 2) * KT);
        }

        const short* Kb = smem + cur * BUFSZ;
        const short* Vb = Kb + KPLANE;

        #pragma unroll
        for (int kc = 0; kc < 2; ++kc) {
            const int cb = kt + kc * 32;
            if (cb > whi || cb + 31 < wlo) continue;   // wave-uniform chunk skip

            // ---- S^T = K·Q^T (two chained 16x16x32 per 16-key half) ----
            f32x4 S[2];
            __builtin_amdgcn_s_setprio(1);
            #pragma unroll
            for (int s = 0; s < 2; ++s) {
                const int krow = (kc * 32 + s * 16 + n15) * KSTR + 8 * g;
                bf16x8 k0f = __builtin_bit_cast(bf16x8, *reinterpret_cast<const short8v*>(&Kb[krow]));
                bf16x8 k1f = __builtin_bit_cast(bf16x8, *reinterpret_cast<const short8v*>(&Kb[krow + 32]));
                f32x4 a = (f32x4){0.f, 0.f, 0.f, 0.f};
                a = MFMA32(k0f, qf[0], a);
                a = MFMA32(k1f, qf[1], a);
                S[s] = a;
            }
            __builtin_amdgcn_s_setprio(0);

            // lane's 8 scores are keys cb+8g .. cb+8g+7:  sc[j] = S[j>>2][j&3]
            // P = exp2(sc) directly (no shift); masked -> exp2(-1e30) == 0
            short8v p8s;
            const bool interior = (cb >= wqmax - WHALF) && (cb + 31 <= wqmin + WHALF);
            if (interior) {
                #pragma unroll
                for (int j = 0; j < 8; ++j)
                    p8s[j] = bf16bits(EXP2F(S[j >> 2][j & 3]));
            } else {
                const int kbase = cb + 8 * g;
                #pragma unroll
                for (int j = 0; j < 8; ++j) {
                    int key = kbase + j;
                    bool valid = (key >= qrow - WHALF) && (key <= qrow + WHALF);
                    p8s[j] = bf16bits(EXP2F(valid ? S[j >> 2][j & 3] : -1e30f));
                }
            }
            bf16x8 p8 = __builtin_bit_cast(bf16x8, p8s);

            // ---- PV: O^T += V^T · P^T via 16x16x32, + register-ones lsum MFMA ----
            __builtin_amdgcn_s_setprio(1);
            #pragma unroll
            for (int dt = 0; dt < 4; ++dt) {
                const int vrow = (dt * 16 + n15) * VSTR + kc * 32 + 8 * g;
                bf16x8 vf = __builtin_bit_cast(bf16x8, *reinterpret_cast<const short8v*>(&Vb[vrow]));
                accO[dt] = MFMA32(vf, p8, accO[dt]);
            }
            accL = MFMA32(ones8, p8, accL);   // row 0 = sum_k p[k] for query n15
            __builtin_amdgcn_s_setprio(0);
        }

        if (i + 1 < nt) __syncthreads();   // next buffer staged by all 4 waves
    }

    // ---- epilogue: lsum sits in accL[0] of the g=0 lane for each query ----
    const float lsum = __shfl(accL[0], n15);   // broadcast from lane id n15 (g=0 block)
    const float inv  = 1.0f / lsum;
    float* op = out + ((size_t)h * SEQ + qrow) * HD;
    #pragma unroll
    for (int dt = 0; dt < 4; ++dt) {
        *reinterpret_cast<f32x4*>(op + dt * 16 + 4 * g) = accO[dt] * inv;
    }
}

extern "C" void kernel_launch(void* const* d_in, const int* in_sizes, int n_in,
                              void* d_out, int out_size, void* d_ws, size_t ws_size,
                              hipStream_t stream) {
    const float* q = (const float*)d_in[0];
    const float* k = (const float*)d_in[1];
    const float* v = (const float*)d_in[2];
    float* out = (float*)d_out;

    dim3 grid(NH * (SEQ / QB));   // 1024 blocks (1D for swizzle)
    dim3 block(256);              // 4 waves
    hipLaunchKernelGGL(swa_mfma12_kernel, grid, block, 0, stream, q, k, v, out);
}

// Round 13
// 26.856 us; speedup vs baseline: 2.7705x; 1.1197x over previous
//
#include <hip/hip_runtime.h>
#include <math.h>

#define SEQ   4096
#define HD    64
#define NH    16
#define WHALF 256
#define QB    128    // queries per block = 8 waves x 16
#define KT    128    // keys staged per barrier
#define KSTR  72     // K plane d-stride (shorts): 144B rows -> b128 R/W at 8-phase bank floor
#define VSTR  136    // V plane key-stride (shorts): 272B rows -> b128 R/W at 8-phase bank floor
#define KPLANE (KT * KSTR)   // 9216 shorts
#define VPLANE (HD * VSTR)   // 8704 shorts
#define BUFSZ  (KPLANE + VPLANE)

typedef __attribute__((ext_vector_type(8))) __bf16 bf16x8;
typedef __attribute__((ext_vector_type(8))) short short8v;
typedef __attribute__((ext_vector_type(4))) float f32x4;

__device__ __forceinline__ short bf16bits(float x) {
    __bf16 b = (__bf16)x;            // RTN
    return __builtin_bit_cast(short, b);
}

#define MFMA32(A, B, C) __builtin_amdgcn_mfma_f32_16x16x32_bf16((A), (B), (C), 0, 0, 0)

#if __has_builtin(__builtin_amdgcn_exp2f)
#define EXP2F(x) __builtin_amdgcn_exp2f(x)
#else
#define EXP2F(x) __exp2f(x)
#endif

__global__ __launch_bounds__(512, 4)
void swa_mfma13_kernel(const float* __restrict__ q,
                       const float* __restrict__ k,
                       const float* __restrict__ v,
                       float* __restrict__ out) {
    // double-buffered: [buf][K plane | V plane] ; 71680 B total -> 2 blocks/CU
    __shared__ short smem[2 * BUFSZ];

    // ---- XCD-aware bijective swizzle: 512 blocks = 8 XCDs x 64; head-major chunks ----
    const int orig = blockIdx.x;
    const int work = ((orig & 7) << 6) + (orig >> 3);
    const int h    = work >> 5;
    const int q0   = (work & 31) * QB;

    const int t    = threadIdx.x;
    const int lane = t & 63;
    const int w    = t >> 6;             // wave 0..7
    const int n15  = lane & 15;
    const int g    = lane >> 4;          // 0..3
    const int qrow = q0 + w * 16 + n15;  // this lane's query

    // scores in log2 domain (fold 1/sqrt(64)*log2(e) into Q); NO max-shift:
    // softmax is shift-invariant and scores are O(10) in the log2 domain.
    const float SCALE = 0.125f * 1.44269504088896340736f;

    // ---- Q fragments (B-operand of S^T = K·Q^T), pre-scaled, plain bf16 ----
    bf16x8 qf[2];
    {
        const float* qp = q + ((size_t)h * SEQ + qrow) * HD;
        #pragma unroll
        for (int c = 0; c < 2; ++c) {
            const float4* p4 = reinterpret_cast<const float4*>(qp + 32 * c + 8 * g);
            float4 a = p4[0], b = p4[1];
            float xs[8] = {a.x, a.y, a.z, a.w, b.x, b.y, b.z, b.w};
            short8v q8;
            #pragma unroll
            for (int j = 0; j < 8; ++j) q8[j] = bf16bits(xs[j] * SCALE);
            qf[c] = __builtin_bit_cast(bf16x8, q8);
        }
    }

    // ones A-fragment for the lsum MFMA (row 0 of A = ones): register constant
    bf16x8 ones8;
    {
        short8v o8;
        const short ov = (n15 == 0) ? (short)0x3F80 : (short)0;
        #pragma unroll
        for (int j = 0; j < 8; ++j) o8[j] = ov;
        ones8 = __builtin_bit_cast(bf16x8, o8);
    }

    f32x4 accO[4];
    #pragma unroll
    for (int dt = 0; dt < 4; ++dt) accO[dt] = (f32x4){0.f, 0.f, 0.f, 0.f};
    f32x4 accL = (f32x4){0.f, 0.f, 0.f, 0.f};   // lsum lands in reg 0 of g=0 lanes

    int k0 = q0 - WHALF;           if (k0 < 0) k0 = 0;
    int k1 = q0 + QB - 1 + WHALF;  if (k1 > SEQ - 1) k1 = SEQ - 1;
    const int nt = (k1 + 1 - k0) >> 7;   // whole 128-key tiles

    const int wqmin = q0 + w * 16;
    const int wqmax = wqmin + 15;
    const int wlo   = wqmin - WHALF;   // wave union window
    const int whi   = wqmax + WHALF;

    const float4* kb4 = reinterpret_cast<const float4*>(k + ((size_t)h * SEQ) * HD);
    const float*  vp  = v + ((size_t)h * SEQ) * HD;

    // ---- single-set 2-tile-deep register prefetch (R10-proven codegen form) ----
    float4 kreg[4];
    float  vreg[16];

    #define LOADT(KTV)                                                        \
        {                                                                     \
            const int kt_ = (KTV);                                            \
            _Pragma("unroll")                                                 \
            for (int i2 = 0; i2 < 4; ++i2)                                    \
                kreg[i2] = kb4[(size_t)kt_ * 16 + t * 4 + i2];                \
            _Pragma("unroll")                                                 \
            for (int j = 0; j < 16; ++j)                                      \
                vreg[j] = vp[(size_t)(kt_ + 16 * w + j) * HD + lane];         \
        }

    // ---- stage regs -> buffer b.  K rows PERMUTED (within each 32-key chunk)
    // so the QK D-fragment hands each lane keys 8g..8g+7 (K=32 PV B-order):
    // physical key p: R = (p & 96) | perm5(p & 31), perm5 validated since R7.
    auto STAGE = [&](int b) {
        short* Kb = smem + b * BUFSZ;
        short* Vb = Kb + KPLANE;

        const int p  = t >> 2;           // physical key row (0..127); 4 threads/row
        const int q5 = p & 31;
        const int R  = (p & 96) + (((q5 >> 2) & 1) << 4) + ((q5 >> 3) << 2) + (q5 & 3);

        const float* kf = reinterpret_cast<const float*>(&kreg[0]);
        short8v k8a, k8b;
        #pragma unroll
        for (int j = 0; j < 8; ++j) {
            k8a[j] = bf16bits(kf[j]);
            k8b[j] = bf16bits(kf[8 + j]);
        }
        *reinterpret_cast<short8v*>(&Kb[R * KSTR + (t & 3) * 16])     = k8a;
        *reinterpret_cast<short8v*>(&Kb[R * KSTR + (t & 3) * 16 + 8]) = k8b;

        short8v v8a, v8b;
        #pragma unroll
        for (int j = 0; j < 8; ++j) {
            v8a[j] = bf16bits(vreg[j]);
            v8b[j] = bf16bits(vreg[8 + j]);
        }
        *reinterpret_cast<short8v*>(&Vb[lane * VSTR + 16 * w])     = v8a;  // [d=lane][key 16w..]
        *reinterpret_cast<short8v*>(&Vb[lane * VSTR + 16 * w + 8]) = v8b;
    };

    LOADT(k0);
    STAGE(0);
    if (nt > 1) LOADT(k0 + KT);
    __syncthreads();

    for (int i = 0; i < nt; ++i) {
        const int kt  = k0 + i * KT;
        const int cur = i & 1;

        if (i + 1 < nt) {
            STAGE(cur ^ 1);
            if (i + 2 < nt) LOADT(k0 + (i + 2) * KT);
        }

        const short* Kb = smem + cur * BUFSZ;
        const short* Vb = Kb + KPLANE;

        // tile fully inside this wave's no-mask zone? (wave-uniform)
        // -> every chunk active AND every score valid: straight-line body,
        //    one basic block, compiler free to software-pipeline chunks.
        const bool nomask = (kt >= wqmax - WHALF) && (kt + KT - 1 <= wqmin + WHALF);

        if (nomask) {
            #pragma unroll
            for (int kc = 0; kc < 4; ++kc) {
                // ---- S^T = K·Q^T ----
                f32x4 S[2];
                __builtin_amdgcn_s_setprio(1);
                #pragma unroll
                for (int s = 0; s < 2; ++s) {
                    const int krow = (kc * 32 + s * 16 + n15) * KSTR + 8 * g;
                    bf16x8 k0f = __builtin_bit_cast(bf16x8, *reinterpret_cast<const short8v*>(&Kb[krow]));
                    bf16x8 k1f = __builtin_bit_cast(bf16x8, *reinterpret_cast<const short8v*>(&Kb[krow + 32]));
                    f32x4 a = (f32x4){0.f, 0.f, 0.f, 0.f};
                    a = MFMA32(k0f, qf[0], a);
                    a = MFMA32(k1f, qf[1], a);
                    S[s] = a;
                }
                __builtin_amdgcn_s_setprio(0);

                // P = exp2(S) — no masking, no branches
                short8v p8s;
                #pragma unroll
                for (int j = 0; j < 8; ++j)
                    p8s[j] = bf16bits(EXP2F(S[j >> 2][j & 3]));
                bf16x8 p8 = __builtin_bit_cast(bf16x8, p8s);

                __builtin_amdgcn_s_setprio(1);
                #pragma unroll
                for (int dt = 0; dt < 4; ++dt) {
                    const int vrow = (dt * 16 + n15) * VSTR + kc * 32 + 8 * g;
                    bf16x8 vf = __builtin_bit_cast(bf16x8, *reinterpret_cast<const short8v*>(&Vb[vrow]));
                    accO[dt] = MFMA32(vf, p8, accO[dt]);
                }
                accL = MFMA32(ones8, p8, accL);
                __builtin_amdgcn_s_setprio(0);
            }
        } else {
            #pragma unroll
            for (int kc = 0; kc < 4; ++kc) {
                const int cb = kt + kc * 32;
                if (cb > whi || cb + 31 < wlo) continue;   // wave-uniform chunk skip

                // ---- S^T = K·Q^T (two chained 16x16x32 per 16-key half) ----
                f32x4 S[2];
                __builtin_amdgcn_s_setprio(1);
                #pragma unroll
                for (int s = 0; s < 2; ++s) {
                    const int krow = (kc * 32 + s * 16 + n15) * KSTR + 8 * g;
                    bf16x8 k0f = __builtin_bit_cast(bf16x8, *reinterpret_cast<const short8v*>(&Kb[krow]));
                    bf16x8 k1f = __builtin_bit_cast(bf16x8, *reinterpret_cast<const short8v*>(&Kb[krow + 32]));
                    f32x4 a = (f32x4){0.f, 0.f, 0.f, 0.f};
                    a = MFMA32(k0f, qf[0], a);
                    a = MFMA32(k1f, qf[1], a);
                    S[s] = a;
                }
                __builtin_amdgcn_s_setprio(0);

                // lane's 8 scores are keys cb+8g .. cb+8g+7:  sc[j] = S[j>>2][j&3]
                // P = exp2(sc) directly (no shift); masked -> exp2(-1e30) == 0
                short8v p8s;
                const bool interior = (cb >= wqmax - WHALF) && (cb + 31 <= wqmin + WHALF);
                if (interior) {
                    #pragma unroll
                    for (int j = 0; j < 8; ++j)
                        p8s[j] = bf16bits(EXP2F(S[j >> 2][j & 3]));
                } else {
                    const int kbase = cb + 8 * g;
                    #pragma unroll
                    for (int j = 0; j < 8; ++j) {
                        int key = kbase + j;
                        bool valid = (key >= qrow - WHALF) && (key <= qrow + WHALF);
                        p8s[j] = bf16bits(EXP2F(valid ? S[j >> 2][j & 3] : -1e30f));
                    }
                }
                bf16x8 p8 = __builtin_bit_cast(bf16x8, p8s);

                // ---- PV: O^T += V^T · P^T via 16x16x32, + register-ones lsum MFMA ----
                __builtin_amdgcn_s_setprio(1);
                #pragma unroll
                for (int dt = 0; dt < 4; ++dt) {
                    const int vrow = (dt * 16 + n15) * VSTR + kc * 32 + 8 * g;
                    bf16x8 vf = __builtin_bit_cast(bf16x8, *reinterpret_cast<const short8v*>(&Vb[vrow]));
                    accO[dt] = MFMA32(vf, p8, accO[dt]);
                }
                accL = MFMA32(ones8, p8, accL);   // row 0 = sum_k p[k] for query n15
                __builtin_amdgcn_s_setprio(0);
            }
        }

        if (i + 1 < nt) __syncthreads();   // next buffer staged by all waves
    }

    // ---- epilogue: lsum sits in accL[0] of the g=0 lane for each query ----
    const float lsum = __shfl(accL[0], n15);   // broadcast from lane id n15 (g=0 block)
    const float inv  = 1.0f / lsum;
    float* op = out + ((size_t)h * SEQ + qrow) * HD;
    #pragma unroll
    for (int dt = 0; dt < 4; ++dt) {
        *reinterpret_cast<f32x4*>(op + dt * 16 + 4 * g) = accO[dt] * inv;
    }
}

extern "C" void kernel_launch(void* const* d_in, const int* in_sizes, int n_in,
                              void* d_out, int out_size, void* d_ws, size_t ws_size,
                              hipStream_t stream) {
    const float* q = (const float*)d_in[0];
    const float* k = (const float*)d_in[1];
    const float* v = (const float*)d_in[2];
    float* out = (float*)d_out;

    dim3 grid(NH * (SEQ / QB));   // 512 blocks (1D for swizzle)
    dim3 block(512);              // 8 waves
    hipLaunchKernelGGL(swa_mfma13_kernel, grid, block, 0, stream, q, k, v, out);
}